// Round 1
// 1095.172 us; speedup vs baseline: 3.3760x; 3.3760x over previous
//
#include <hip/hip_runtime.h>
#include <math.h>

typedef unsigned short u16;
typedef __bf16 bf16x8 __attribute__((ext_vector_type(8)));
typedef float f32x4 __attribute__((ext_vector_type(4)));

#define MROWS 12608   // B*N = 64*197
#define NSEQ  197
#define NHEAD 12
#define DMODEL 768

__device__ __forceinline__ u16 f2bf(float f) {
    unsigned u = __float_as_uint(f);
    u += 0x7FFFu + ((u >> 16) & 1u);   // RNE
    return (u16)(u >> 16);
}
__device__ __forceinline__ float bf2f(u16 v) { return __uint_as_float(((unsigned)v) << 16); }

// build a bf16x8 A/B fragment from 8 consecutive fp32 values
__device__ __forceinline__ bf16x8 cvt8(const float* p) {
    float4 a = *(const float4*)p;
    float4 b = *(const float4*)(p + 4);
    union { bf16x8 v; u16 s[8]; } t;
    t.s[0] = f2bf(a.x); t.s[1] = f2bf(a.y); t.s[2] = f2bf(a.z); t.s[3] = f2bf(a.w);
    t.s[4] = f2bf(b.x); t.s[5] = f2bf(b.y); t.s[6] = f2bf(b.z); t.s[7] = f2bf(b.w);
    return t.v;
}

// async 16B global -> LDS (HW: lds dest = wave-uniform base + lane*16)
__device__ __forceinline__ void g2l16(const u16* g, u16* l) {
    __builtin_amdgcn_global_load_lds((const __attribute__((address_space(1))) unsigned*)g,
                                     (__attribute__((address_space(3))) unsigned*)l,
                                     16, 0, 0);
}

// ---------------- layernorm: fp32 in -> bf16 out, one wave per row ----------
__global__ __launch_bounds__(256) void ln_rows(const float* x,
                                               const float* g,
                                               const float* bta,
                                               u16* o, int Mr) {
    int w = threadIdx.x >> 6, lane = threadIdx.x & 63;
    int row = blockIdx.x * 4 + w;
    if (row >= Mr) return;
    const float* xr = x + (size_t)row * DMODEL;
    float vals[12];
    for (int i = 0; i < 6; ++i) {
        float2 xx = *(const float2*)(xr + i * 128 + lane * 2);
        vals[2 * i] = xx.x; vals[2 * i + 1] = xx.y;
    }
    float s = 0.f;
    for (int i = 0; i < 12; ++i) s += vals[i];
    for (int off = 1; off < 64; off <<= 1) s += __shfl_xor(s, off, 64);
    float mu = s * (1.f / 768.f);
    float v2 = 0.f;
    for (int i = 0; i < 12; ++i) { float d = vals[i] - mu; v2 += d * d; }
    for (int off = 1; off < 64; off <<= 1) v2 += __shfl_xor(v2, off, 64);
    float rstd = rsqrtf(v2 * (1.f / 768.f) + 1e-5f);
    u16* orow = o + (size_t)row * DMODEL;
    for (int i = 0; i < 6; ++i) {
        int c = i * 128 + lane * 2;
        float2 gg = *(const float2*)(g + c);
        float2 bb = *(const float2*)(bta + c);
        float y0 = (vals[2 * i] - mu) * rstd * gg.x + bb.x;
        float y1 = (vals[2 * i + 1] - mu) * rstd * gg.y + bb.y;
        *(unsigned*)(orow + c) = (unsigned)f2bf(y0) | ((unsigned)f2bf(y1) << 16);
    }
}

// -------- weight transpose: dst[n][k] (bf16) = src[k][n] (fp32) -------------
// grid (K/32, N/32), 256 threads
__global__ __launch_bounds__(256) void wtrans(const float* __restrict__ src,
                                              u16* __restrict__ dst,
                                              int ldsrc, int lddst) {
    __shared__ float t[32][33];
    int c = threadIdx.x & 31, r0 = threadIdx.x >> 5;
    int k0 = blockIdx.x * 32, n0 = blockIdx.y * 32;
#pragma unroll
    for (int i = 0; i < 4; ++i)
        t[r0 + 8 * i][c] = src[(size_t)(k0 + r0 + 8 * i) * ldsrc + n0 + c];
    __syncthreads();
#pragma unroll
    for (int i = 0; i < 4; ++i)
        dst[(size_t)(n0 + r0 + 8 * i) * lddst + k0 + c] = f2bf(t[c][r0 + 8 * i]);
}

// ---- GEMM core: acc = A[M,K](bf16) @ BT[N,K](bf16)^T over a BMx128 tile ----
// BM=128: 4 waves 2x2, each 64x64 (acc[4][4]); BM=64: each wave 32x64 (acc[2][4]).
// double-buffered LDS staging via global_load_lds (T3 minimum 2-phase).
template <int BM>
__device__ __forceinline__ void gemm_core(
    const u16* __restrict__ A, const u16* __restrict__ BT,
    int M, int K, int lda, int ldb,
    u16* aS, u16* bS, f32x4 (&acc)[BM / 32][4])
{
    constexpr int MT  = BM / 32;   // m-fragments per wave
    constexpr int LPA = BM / 64;   // 1KB A-stage loads per wave
    int tid = threadIdx.x, w = tid >> 6, lane = tid & 63;
    int row0 = blockIdx.x * BM, col0 = blockIdx.y * 128;
    int kk = (lane & 3) * 8, rsub = lane >> 2;

    // per-lane global source pointers + wave-uniform LDS bases (u16 elements)
    const u16* aG[LPA]; int lA[LPA];
#pragma unroll
    for (int i = 0; i < LPA; ++i) {
        int sr = (w * LPA + i) * 16 + rsub;
        int gr = row0 + sr; if (gr > M - 1) gr = M - 1;   // tail clamp (store guarded)
        aG[i] = A + (size_t)gr * lda + kk;
        lA[i] = (w * LPA + i) * 512;
    }
    const u16* bG[2]; int lB[2];
#pragma unroll
    for (int i = 0; i < 2; ++i) {
        int sc = (w * 2 + i) * 16 + rsub;                 // N always multiple of 128
        bG[i] = BT + (size_t)(col0 + sc) * ldb + kk;
        lB[i] = (w * 2 + i) * 512;
    }
    int wmB = (w >> 1) * (BM / 2), wnB = (w & 1) * 64;
    int lrow = lane & 15, lq = lane >> 4;

    const f32x4 z = {0.f, 0.f, 0.f, 0.f};
#pragma unroll
    for (int i = 0; i < MT; ++i)
#pragma unroll
        for (int j = 0; j < 4; ++j) acc[i][j] = z;

    // prologue: stage K-step 0 into buffer 0
#pragma unroll
    for (int i = 0; i < LPA; ++i) g2l16(aG[i], aS + lA[i]);
#pragma unroll
    for (int i = 0; i < 2; ++i)  g2l16(bG[i], bS + lB[i]);
    __syncthreads();

    int nt = K >> 5, cur = 0;
    for (int t = 0; t < nt; ++t) {
        int nxt = cur ^ 1;
        if (t + 1 < nt) {           // issue next-tile stage BEFORE consuming current
            int ko = (t + 1) << 5;
#pragma unroll
            for (int i = 0; i < LPA; ++i) g2l16(aG[i] + ko, aS + nxt * (BM * 32) + lA[i]);
#pragma unroll
            for (int i = 0; i < 2; ++i)  g2l16(bG[i] + ko, bS + nxt * 4096 + lB[i]);
        }
        const u16* aC = aS + cur * (BM * 32);
        const u16* bC = bS + cur * 4096;
        bf16x8 af[MT], bfr[4];
#pragma unroll
        for (int mt = 0; mt < MT; ++mt)
            af[mt] = *(const bf16x8*)(aC + (wmB + mt * 16 + lrow) * 32 + lq * 8);
#pragma unroll
        for (int n2 = 0; n2 < 4; ++n2)
            bfr[n2] = *(const bf16x8*)(bC + (wnB + n2 * 16 + lrow) * 32 + lq * 8);
#pragma unroll
        for (int mt = 0; mt < MT; ++mt)
#pragma unroll
            for (int n2 = 0; n2 < 4; ++n2)
                acc[mt][n2] = __builtin_amdgcn_mfma_f32_16x16x32_bf16(af[mt], bfr[n2], acc[mt][n2], 0, 0, 0);
        __syncthreads();            // drains prefetch (vmcnt) + read completion
        cur = nxt;
    }
}

// generic epilogue wrapper: bias, scale, gelu, resid, fp32 and/or bf16 out
template <int BM>
__global__ __launch_bounds__(256) void gemm_std(
    const u16* __restrict__ A, const u16* __restrict__ BT,
    float* Cf, u16* Cb, const float* bias, const float* resid,
    int M, int K, int lda, int ldb, int ldc, float scale, int do_gelu)
{
    __shared__ __align__(16) u16 aS[2 * BM * 32];
    __shared__ __align__(16) u16 bS[2 * 128 * 32];
    constexpr int MT = BM / 32;
    f32x4 acc[MT][4];
    gemm_core<BM>(A, BT, M, K, lda, ldb, aS, bS, acc);

    int tid = threadIdx.x, w = tid >> 6, lane = tid & 63;
    int row0 = blockIdx.x * BM, col0 = blockIdx.y * 128;
    int wmB = (w >> 1) * (BM / 2), wnB = (w & 1) * 64;
    int lrow = lane & 15, lq = lane >> 4;
#pragma unroll
    for (int mt = 0; mt < MT; ++mt) {
        int gmb = row0 + wmB + mt * 16 + lq * 4;
#pragma unroll
        for (int n2 = 0; n2 < 4; ++n2) {
            int gc = col0 + wnB + n2 * 16 + lrow;
            float bv = bias ? bias[gc] : 0.f;
            for (int r = 0; r < 4; ++r) {
                int gm = gmb + r;
                if (gm < M) {
                    float v0 = (acc[mt][n2][r] + bv) * scale;
                    if (do_gelu) v0 = 0.5f * v0 * (1.f + erff(v0 * 0.70710678118654752f));
                    if (resid) v0 += resid[(size_t)gm * ldc + gc];
                    if (Cf) Cf[(size_t)gm * ldc + gc] = v0;
                    if (Cb) Cb[(size_t)gm * ldc + gc] = f2bf(v0);
                }
            }
        }
    }
}

// fused QKV epilogue: N=2304 = [q | k | v]; q fp32*0.125, k fp32, v bf16
__global__ __launch_bounds__(256) void gemm_qkv(
    const u16* __restrict__ A, const u16* __restrict__ BT,
    float* qo, float* ko, u16* vo,
    const float* bq, const float* bk, const float* bvv, int M)
{
    __shared__ __align__(16) u16 aS[2 * 128 * 32];
    __shared__ __align__(16) u16 bS[2 * 128 * 32];
    f32x4 acc[4][4];
    gemm_core<128>(A, BT, M, 768, 768, 768, aS, bS, acc);

    int tid = threadIdx.x, w = tid >> 6, lane = tid & 63;
    int row0 = blockIdx.x * 128, col0 = blockIdx.y * 128;
    int wmB = (w >> 1) * 64, wnB = (w & 1) * 64;
    int lrow = lane & 15, lq = lane >> 4;
#pragma unroll
    for (int mt = 0; mt < 4; ++mt) {
        int gmb = row0 + wmB + mt * 16 + lq * 4;
#pragma unroll
        for (int n2 = 0; n2 < 4; ++n2) {
            int gc = col0 + wnB + n2 * 16 + lrow;
            int j = gc / 768;                 // uniform per fragment (16 | 768)
            int c = gc - j * 768;
            const float* bp = (j == 0) ? bq : (j == 1) ? bk : bvv;
            float bb = bp[c];
            for (int r = 0; r < 4; ++r) {
                int gm = gmb + r;
                if (gm < M) {
                    float v0 = acc[mt][n2][r] + bb;
                    size_t off = (size_t)gm * 768 + c;
                    if (j == 0)      qo[off] = v0 * 0.125f;
                    else if (j == 1) ko[off] = v0;
                    else             vo[off] = f2bf(v0);
                }
            }
        }
    }
}

// ------- attention scores + softmax: q,k fp32 -> probs fp32 -----------------
__global__ __launch_bounds__(256) void attn_scores(const float* q,
                                                   const float* k,
                                                   float* attn) {
    __shared__ float S[4][16 * 208];
    __shared__ float mxs[4][16];
    __shared__ float rls[4][16];
    int bid = blockIdx.x;
    int bh = bid >> 2, mb = bid & 3;
    int b = bh / NHEAD, hh = bh - b * NHEAD;
    int tid = threadIdx.x, w = tid >> 6, lane = tid & 63;
    int lrow = lane & 15, lq = lane >> 4;
    int mtile = mb * 4 + w;   // 0..15, valid < 13

    if (mtile < 13) {
        int gm = mtile * 16 + lrow; if (gm > 196) gm = 196;
        const float* qrow = q + (size_t)(b * NSEQ + gm) * DMODEL + hh * 64;
        bf16x8 aq0 = cvt8(qrow + lq * 8);
        bf16x8 aq1 = cvt8(qrow + 32 + lq * 8);
        for (int nt = 0; nt < 13; ++nt) {
            int gn = nt * 16 + lrow; if (gn > 196) gn = 196;
            const float* krow = k + (size_t)(b * NSEQ + gn) * DMODEL + hh * 64;
            bf16x8 bk0 = cvt8(krow + lq * 8);
            bf16x8 bk1 = cvt8(krow + 32 + lq * 8);
            f32x4 a = {0.f, 0.f, 0.f, 0.f};
            a = __builtin_amdgcn_mfma_f32_16x16x32_bf16(aq0, bk0, a, 0, 0, 0);
            a = __builtin_amdgcn_mfma_f32_16x16x32_bf16(aq1, bk1, a, 0, 0, 0);
            for (int r = 0; r < 4; ++r)
                S[w][(lq * 4 + r) * 208 + nt * 16 + lrow] = a[r];
        }
    }
    __syncthreads();
    if (mtile < 13) {
        int r = lane >> 2, c0 = lane & 3;
        int gm = mtile * 16 + r;
        float mx = -1e30f, sm = 0.f;
        if (gm < 197)
            for (int c = c0; c < 197; c += 4) mx = fmaxf(mx, S[w][r * 208 + c]);
        mx = fmaxf(mx, __shfl_xor(mx, 1, 64));
        mx = fmaxf(mx, __shfl_xor(mx, 2, 64));
        if (gm < 197)
            for (int c = c0; c < 197; c += 4) sm += __expf(S[w][r * 208 + c] - mx);
        sm += __shfl_xor(sm, 1, 64);
        sm += __shfl_xor(sm, 2, 64);
        if ((lane & 3) == 0) { mxs[w][r] = mx; rls[w][r] = 1.f / sm; }
    }
    __syncthreads();
    if (mtile < 13) {
        size_t base = (size_t)(b * NHEAD + hh) * (NSEQ * NSEQ);
        for (int it = 0; it < 50; ++it) {
            int idx = it * 64 + lane;   // over 16*197 = 3152
            if (idx < 3152) {
                int row = idx / 197;
                int col = idx - row * 197;
                int gm = mtile * 16 + row;
                if (gm < 197) {
                    float p = __expf(S[w][row * 208 + col] - mxs[w][row]) * rls[w][row];
                    attn[base + (size_t)gm * 197 + col] = p;
                }
            }
        }
    }
}

// ------- PV: probs fp32 @ v bf16 -> out0 fp32 + bf16 copy to ws -------------
__global__ __launch_bounds__(256) void attn_pv(const float* attn,
                                               const u16* v,
                                               float* outf, u16* outb) {
    __shared__ __align__(16) u16 vT[64 * 224];
    __shared__ __align__(16) u16 P[4][16 * 224];
    int bh = blockIdx.x;
    int b = bh / NHEAD, hh = bh - b * NHEAD;
    int tid = threadIdx.x, w = tid >> 6, lane = tid & 63;
    int lrow = lane & 15, lq = lane >> 4;
    {
        int cg = (tid & 7) * 8;
        int rb = tid >> 3;
        for (int i = 0; i < 7; ++i) {
            int r = rb + i * 32;
            union { uint4 q; u16 s[8]; } tmp;
            if (r < 197) {
                tmp.q = *(const uint4*)(v + (size_t)(b * NSEQ + r) * DMODEL + hh * 64 + cg);
            } else {
                tmp.q.x = tmp.q.y = tmp.q.z = tmp.q.w = 0u;
            }
            for (int j = 0; j < 8; ++j) vT[(cg + j) * 224 + r] = tmp.s[j];
        }
    }
    __syncthreads();
    size_t pbase = (size_t)(b * NHEAD + hh) * (NSEQ * NSEQ);
    const f32x4 zf = {0.f, 0.f, 0.f, 0.f};
    for (int it = 0; it < 4; ++it) {
        int mtile = w + it * 4;
        bool valid = (mtile < 13);
        if (valid) {
            for (int ii = 0; ii < 56; ++ii) {     // 16*224 = 3584
                int idx = ii * 64 + lane;
                int row = idx / 224;
                int col = idx - row * 224;
                u16 val = 0;
                if (col < 197) {
                    int gm = mtile * 16 + row; if (gm > 196) gm = 196;
                    val = f2bf(attn[pbase + (size_t)gm * 197 + col]);
                }
                P[w][idx] = val;
            }
        }
        __syncthreads();
        if (valid) {
            f32x4 acc[4];
            for (int nt = 0; nt < 4; ++nt) acc[nt] = zf;
            for (int ks = 0; ks < 7; ++ks) {
                bf16x8 af = *(const bf16x8*)(&P[w][lrow * 224 + ks * 32 + lq * 8]);
                for (int nt = 0; nt < 4; ++nt) {
                    bf16x8 bv = *(const bf16x8*)(&vT[(nt * 16 + lrow) * 224 + ks * 32 + lq * 8]);
                    acc[nt] = __builtin_amdgcn_mfma_f32_16x16x32_bf16(af, bv, acc[nt], 0, 0, 0);
                }
            }
            for (int nt = 0; nt < 4; ++nt) {
                int gcol = hh * 64 + nt * 16 + lrow;
                for (int r = 0; r < 4; ++r) {
                    int gm = mtile * 16 + lq * 4 + r;
                    if (gm < 197) {
                        size_t off = (size_t)(b * NSEQ + gm) * DMODEL + gcol;
                        outf[off] = acc[nt][r];
                        outb[off] = f2bf(acc[nt][r]);
                    }
                }
            }
        }
        __syncthreads();
    }
}

extern "C" void kernel_launch(void* const* d_in, const int* in_sizes, int n_in,
                              void* d_out, int out_size, void* d_ws, size_t ws_size,
                              hipStream_t stream) {
    const float* x    = (const float*)d_in[0];
    const float* ln1g = (const float*)d_in[1];
    const float* ln1b = (const float*)d_in[2];
    const float* wq   = (const float*)d_in[3];
    const float* bq   = (const float*)d_in[4];
    const float* wk   = (const float*)d_in[5];
    const float* bk   = (const float*)d_in[6];
    const float* wv   = (const float*)d_in[7];
    const float* bv   = (const float*)d_in[8];
    const float* wo   = (const float*)d_in[9];
    const float* bo   = (const float*)d_in[10];
    const float* ln2g = (const float*)d_in[11];
    const float* ln2b = (const float*)d_in[12];
    const float* w1   = (const float*)d_in[13];
    const float* b1   = (const float*)d_in[14];
    const float* w2   = (const float*)d_in[15];
    const float* b2   = (const float*)d_in[16];

    float* out     = (float*)d_out;
    float* preproj = out;                 // output 0: 12608*768 fp32
    float* hidden  = out + 9682944;       // output 1: 12608*768 fp32
    float* attnw   = out + 19365888;      // output 2: 64*12*197*197 fp32

    u16* bufA = (u16*)d_ws;               // h -> attn_out(bf16) -> hsn
    u16* bufB = bufA + 9682944;           // v -> woT -> gelu chunk (+wT slots)

    // qkvT [2304][768] bf16 stashed in attnw region (dead until attn_scores)
    u16* qkvT = (u16*)attnw;

    // MLP weight-transpose slots: ws tail if available, else carved from bufB
    long long tailElems = (long long)(ws_size >> 1) - 19365888LL;
    int CH; u16* w1T;
    if (tailElems >= 1179648LL)      { CH = 768; w1T = bufB + 9682944; }
    else if (tailElems >= 786432LL)  { CH = 512; w1T = bufB + 9682944; }
    else                             { CH = 512; w1T = bufB + 6455296; } // past gelu chunk
    u16* w2T = w1T + (size_t)CH * 768;
    int NCH = 3072 / CH;

    // LN1: x -> bufA (bf16)
    ln_rows<<<3152, 256, 0, stream>>>(x, ln1g, ln1b, bufA, MROWS);
    // transpose wq|wk|wv -> qkvT (bf16, [n][k])
    wtrans<<<dim3(24, 24), 256, 0, stream>>>(wq, qkvT,           768, 768);
    wtrans<<<dim3(24, 24), 256, 0, stream>>>(wk, qkvT + 589824,  768, 768);
    wtrans<<<dim3(24, 24), 256, 0, stream>>>(wv, qkvT + 1179648, 768, 768);
    // fused QKV: q(fp32*0.125)->preproj, k(fp32)->hidden, v(bf16)->bufB
    gemm_qkv<<<dim3(99, 18), 256, 0, stream>>>(bufA, qkvT, preproj, hidden, bufB,
                                               bq, bk, bv, MROWS);
    // attention: probs fp32 -> attnw (overwrites qkvT stash completely)
    attn_scores<<<3072, 256, 0, stream>>>(preproj, hidden, attnw);
    // PV: -> preproj fp32 (final output 0) + bf16 copy into bufA
    attn_pv<<<768, 256, 0, stream>>>(attnw, bufB, preproj, bufA);
    // woT into bufB (v dead), then out-proj + residual(x) -> hidden
    wtrans<<<dim3(24, 24), 256, 0, stream>>>(wo, bufB, 768, 768);
    gemm_std<64><<<dim3(197, 6), 256, 0, stream>>>(bufA, bufB, hidden, nullptr, bo, x,
                                                   MROWS, 768, 768, 768, 768, 1.f, 0);
    // LN2: hidden -> bufA (bf16 hsn)
    ln_rows<<<3152, 256, 0, stream>>>(hidden, ln2g, ln2b, bufA, MROWS);
    // MLP in DFF chunks of CH: transpose chunk weights, gemm1(gelu,bf16), gemm2(+resid)
    for (int ci = 0; ci < NCH; ++ci) {
        wtrans<<<dim3(24, CH / 32), 256, 0, stream>>>(w1 + ci * CH, w1T, 3072, 768);
        wtrans<<<dim3(CH / 32, 24), 256, 0, stream>>>(w2 + (size_t)ci * CH * 768, w2T, 768, CH);
        gemm_std<64><<<dim3(197, CH / 128), 256, 0, stream>>>(
            bufA, w1T, nullptr, bufB, b1 + ci * CH, nullptr,
            MROWS, 768, 768, 768, CH, 1.f, 1);
        gemm_std<64><<<dim3(197, 6), 256, 0, stream>>>(
            bufB, w2T, hidden, nullptr, (ci == 0) ? b2 : nullptr, hidden,
            MROWS, CH, CH, CH, 768, 1.f, 0);
    }
}

// Round 2
// 938.096 us; speedup vs baseline: 3.9413x; 1.1674x over previous
//
#include <hip/hip_runtime.h>
#include <math.h>

typedef unsigned short u16;
typedef __bf16 bf16x8 __attribute__((ext_vector_type(8)));
typedef float f32x4 __attribute__((ext_vector_type(4)));

#define MROWS 12608   // B*N = 64*197
#define NSEQ  197
#define NHEAD 12
#define DMODEL 768

__device__ __forceinline__ u16 f2bf(float f) {
    unsigned u = __float_as_uint(f);
    u += 0x7FFFu + ((u >> 16) & 1u);   // RNE
    return (u16)(u >> 16);
}
__device__ __forceinline__ float bf2f(u16 v) { return __uint_as_float(((unsigned)v) << 16); }

// build a bf16x8 A/B fragment from 8 consecutive fp32 values
__device__ __forceinline__ bf16x8 cvt8(const float* p) {
    float4 a = *(const float4*)p;
    float4 b = *(const float4*)(p + 4);
    union { bf16x8 v; u16 s[8]; } t;
    t.s[0] = f2bf(a.x); t.s[1] = f2bf(a.y); t.s[2] = f2bf(a.z); t.s[3] = f2bf(a.w);
    t.s[4] = f2bf(b.x); t.s[5] = f2bf(b.y); t.s[6] = f2bf(b.z); t.s[7] = f2bf(b.w);
    return t.v;
}

// async 16B global -> LDS (HW: lds dest = wave-uniform base + lane*16)
__device__ __forceinline__ void g2l16(const u16* g, u16* l) {
    __builtin_amdgcn_global_load_lds((const __attribute__((address_space(1))) unsigned*)g,
                                     (__attribute__((address_space(3))) unsigned*)l,
                                     16, 0, 0);
}

// ---------------- layernorm: fp32 in -> bf16 out, one wave per row ----------
__global__ __launch_bounds__(256) void ln_rows(const float* x,
                                               const float* g,
                                               const float* bta,
                                               u16* o, int Mr) {
    int w = threadIdx.x >> 6, lane = threadIdx.x & 63;
    int row = blockIdx.x * 4 + w;
    if (row >= Mr) return;
    const float* xr = x + (size_t)row * DMODEL;
    float vals[12];
    for (int i = 0; i < 6; ++i) {
        float2 xx = *(const float2*)(xr + i * 128 + lane * 2);
        vals[2 * i] = xx.x; vals[2 * i + 1] = xx.y;
    }
    float s = 0.f;
    for (int i = 0; i < 12; ++i) s += vals[i];
    for (int off = 1; off < 64; off <<= 1) s += __shfl_xor(s, off, 64);
    float mu = s * (1.f / 768.f);
    float v2 = 0.f;
    for (int i = 0; i < 12; ++i) { float d = vals[i] - mu; v2 += d * d; }
    for (int off = 1; off < 64; off <<= 1) v2 += __shfl_xor(v2, off, 64);
    float rstd = rsqrtf(v2 * (1.f / 768.f) + 1e-5f);
    u16* orow = o + (size_t)row * DMODEL;
    for (int i = 0; i < 6; ++i) {
        int c = i * 128 + lane * 2;
        float2 gg = *(const float2*)(g + c);
        float2 bb = *(const float2*)(bta + c);
        float y0 = (vals[2 * i] - mu) * rstd * gg.x + bb.x;
        float y1 = (vals[2 * i + 1] - mu) * rstd * gg.y + bb.y;
        *(unsigned*)(orow + c) = (unsigned)f2bf(y0) | ((unsigned)f2bf(y1) << 16);
    }
}

// -------- weight transpose: dst[n][k] (bf16) = src[k][n] (fp32) -------------
__global__ __launch_bounds__(256) void wtrans(const float* __restrict__ src,
                                              u16* __restrict__ dst,
                                              int ldsrc, int lddst) {
    __shared__ float t[32][33];
    int c = threadIdx.x & 31, r0 = threadIdx.x >> 5;
    int k0 = blockIdx.x * 32, n0 = blockIdx.y * 32;
#pragma unroll
    for (int i = 0; i < 4; ++i)
        t[r0 + 8 * i][c] = src[(size_t)(k0 + r0 + 8 * i) * ldsrc + n0 + c];
    __syncthreads();
#pragma unroll
    for (int i = 0; i < 4; ++i)
        dst[(size_t)(n0 + r0 + 8 * i) * lddst + k0 + c] = f2bf(t[c][r0 + 8 * i]);
}

// ---- GEMM core: acc = A[M,K](bf16) @ BT[N,K](bf16)^T over a BMx128 tile ----
template <int BM>
__device__ __forceinline__ void gemm_core(
    const u16* __restrict__ A, const u16* __restrict__ BT,
    int M, int K, int lda, int ldb,
    u16* aS, u16* bS, f32x4 (&acc)[BM / 32][4])
{
    constexpr int MT  = BM / 32;
    constexpr int LPA = BM / 64;
    int tid = threadIdx.x, w = tid >> 6, lane = tid & 63;
    int row0 = blockIdx.x * BM, col0 = blockIdx.y * 128;
    int kk = (lane & 3) * 8, rsub = lane >> 2;

    const u16* aG[LPA]; int lA[LPA];
#pragma unroll
    for (int i = 0; i < LPA; ++i) {
        int sr = (w * LPA + i) * 16 + rsub;
        int gr = row0 + sr; if (gr > M - 1) gr = M - 1;
        aG[i] = A + (size_t)gr * lda + kk;
        lA[i] = (w * LPA + i) * 512;
    }
    const u16* bG[2]; int lB[2];
#pragma unroll
    for (int i = 0; i < 2; ++i) {
        int sc = (w * 2 + i) * 16 + rsub;
        bG[i] = BT + (size_t)(col0 + sc) * ldb + kk;
        lB[i] = (w * 2 + i) * 512;
    }
    int wmB = (w >> 1) * (BM / 2), wnB = (w & 1) * 64;
    int lrow = lane & 15, lq = lane >> 4;

    const f32x4 z = {0.f, 0.f, 0.f, 0.f};
#pragma unroll
    for (int i = 0; i < MT; ++i)
#pragma unroll
        for (int j = 0; j < 4; ++j) acc[i][j] = z;

#pragma unroll
    for (int i = 0; i < LPA; ++i) g2l16(aG[i], aS + lA[i]);
#pragma unroll
    for (int i = 0; i < 2; ++i)  g2l16(bG[i], bS + lB[i]);
    __syncthreads();

    int nt = K >> 5, cur = 0;
    for (int t = 0; t < nt; ++t) {
        int nxt = cur ^ 1;
        if (t + 1 < nt) {
            int ko = (t + 1) << 5;
#pragma unroll
            for (int i = 0; i < LPA; ++i) g2l16(aG[i] + ko, aS + nxt * (BM * 32) + lA[i]);
#pragma unroll
            for (int i = 0; i < 2; ++i)  g2l16(bG[i] + ko, bS + nxt * 4096 + lB[i]);
        }
        const u16* aC = aS + cur * (BM * 32);
        const u16* bC = bS + cur * 4096;
        bf16x8 af[MT], bfr[4];
#pragma unroll
        for (int mt = 0; mt < MT; ++mt)
            af[mt] = *(const bf16x8*)(aC + (wmB + mt * 16 + lrow) * 32 + lq * 8);
#pragma unroll
        for (int n2 = 0; n2 < 4; ++n2)
            bfr[n2] = *(const bf16x8*)(bC + (wnB + n2 * 16 + lrow) * 32 + lq * 8);
#pragma unroll
        for (int mt = 0; mt < MT; ++mt)
#pragma unroll
            for (int n2 = 0; n2 < 4; ++n2)
                acc[mt][n2] = __builtin_amdgcn_mfma_f32_16x16x32_bf16(af[mt], bfr[n2], acc[mt][n2], 0, 0, 0);
        __syncthreads();
        cur = nxt;
    }
}

template <int BM>
__global__ __launch_bounds__(256) void gemm_std(
    const u16* __restrict__ A, const u16* __restrict__ BT,
    float* Cf, u16* Cb, const float* bias, const float* resid,
    int M, int K, int lda, int ldb, int ldc, float scale, int do_gelu)
{
    __shared__ __align__(16) u16 aS[2 * BM * 32];
    __shared__ __align__(16) u16 bS[2 * 128 * 32];
    constexpr int MT = BM / 32;
    f32x4 acc[MT][4];
    gemm_core<BM>(A, BT, M, K, lda, ldb, aS, bS, acc);

    int tid = threadIdx.x, w = tid >> 6, lane = tid & 63;
    int row0 = blockIdx.x * BM, col0 = blockIdx.y * 128;
    int wmB = (w >> 1) * (BM / 2), wnB = (w & 1) * 64;
    int lrow = lane & 15, lq = lane >> 4;
#pragma unroll
    for (int mt = 0; mt < MT; ++mt) {
        int gmb = row0 + wmB + mt * 16 + lq * 4;
#pragma unroll
        for (int n2 = 0; n2 < 4; ++n2) {
            int gc = col0 + wnB + n2 * 16 + lrow;
            float bv = bias ? bias[gc] : 0.f;
            for (int r = 0; r < 4; ++r) {
                int gm = gmb + r;
                if (gm < M) {
                    float v0 = (acc[mt][n2][r] + bv) * scale;
                    if (do_gelu) v0 = 0.5f * v0 * (1.f + erff(v0 * 0.70710678118654752f));
                    if (resid) v0 += resid[(size_t)gm * ldc + gc];
                    if (Cf) Cf[(size_t)gm * ldc + gc] = v0;
                    if (Cb) Cb[(size_t)gm * ldc + gc] = f2bf(v0);
                }
            }
        }
    }
}

// fused QKV epilogue: N=2304 = [q | k | v]; q fp32*0.125, k fp32, v bf16
__global__ __launch_bounds__(256) void gemm_qkv(
    const u16* __restrict__ A, const u16* __restrict__ BT,
    float* qo, float* ko, u16* vo,
    const float* bq, const float* bk, const float* bvv, int M)
{
    __shared__ __align__(16) u16 aS[2 * 128 * 32];
    __shared__ __align__(16) u16 bS[2 * 128 * 32];
    f32x4 acc[4][4];
    gemm_core<128>(A, BT, M, 768, 768, 768, aS, bS, acc);

    int tid = threadIdx.x, w = tid >> 6, lane = tid & 63;
    int row0 = blockIdx.x * 128, col0 = blockIdx.y * 128;
    int wmB = (w >> 1) * 64, wnB = (w & 1) * 64;
    int lrow = lane & 15, lq = lane >> 4;
#pragma unroll
    for (int mt = 0; mt < 4; ++mt) {
        int gmb = row0 + wmB + mt * 16 + lq * 4;
#pragma unroll
        for (int n2 = 0; n2 < 4; ++n2) {
            int gc = col0 + wnB + n2 * 16 + lrow;
            int j = gc / 768;
            int c = gc - j * 768;
            const float* bp = (j == 0) ? bq : (j == 1) ? bk : bvv;
            float bb = bp[c];
            for (int r = 0; r < 4; ++r) {
                int gm = gmb + r;
                if (gm < M) {
                    float v0 = acc[mt][n2][r] + bb;
                    size_t off = (size_t)gm * 768 + c;
                    if (j == 0)      qo[off] = v0 * 0.125f;
                    else if (j == 1) ko[off] = v0;
                    else             vo[off] = f2bf(v0);
                }
            }
        }
    }
}

// ---- fused attention: scores + softmax + probs-out + PV, one (b,h) slice ---
// grid = 2*(B*H); block bid: bh = bid>>1, mb = bid&1 (mtiles 0-6 / 7-12).
// Per wave: 16-row m-tile. Scores in registers; in-register softmax
// (row = 16 lanes sharing lq, 4x shfl_xor); probs written once (write-only);
// P -> per-wave swizzled LDS (no barriers in main loop); PV immediately.
__global__ __launch_bounds__(256) void attn_fused(const float* q, const float* k,
                                                  const u16* v, float* attnw,
                                                  float* outf, u16* outb) {
    __shared__ __align__(16) u16 vT[64 * 224];      // [d][k] bf16, zero-padded k>=197
    __shared__ __align__(16) u16 P[4][16 * 224];    // per-wave [m][k], k ^ ((m>>2)<<3)
    int bid = blockIdx.x;
    int bh = bid >> 1, mb = bid & 1;
    int b = bh / NHEAD, hh = bh - b * NHEAD;
    int tid = threadIdx.x, w = tid >> 6, lane = tid & 63;
    int lrow = lane & 15, lq = lane >> 4;

    // stage V^T (transpose, zero-pad rows >=197) — same as previous attn_pv
    {
        int cg = (tid & 7) * 8;
        int rb = tid >> 3;
        for (int i = 0; i < 7; ++i) {
            int r = rb + i * 32;
            union { uint4 qv; u16 s[8]; } tmp;
            if (r < 197) {
                tmp.qv = *(const uint4*)(v + (size_t)(b * NSEQ + r) * DMODEL + hh * 64 + cg);
            } else {
                tmp.qv.x = tmp.qv.y = tmp.qv.z = tmp.qv.w = 0u;
            }
            for (int j = 0; j < 8; ++j) vT[(cg + j) * 224 + r] = tmp.s[j];
        }
    }
    // zero-fill P pad k in [208,224) (swizzled positions); persists all rounds
    u16* Pw = &P[w][0];
#pragma unroll
    for (int r = 0; r < 4; ++r) {
        int m = lq * 4 + r;
        Pw[m * 224 + ((208 + lrow) ^ (lq << 3))] = 0;
    }
    __syncthreads();   // vT ready

    size_t pbase = (size_t)bh * (NSEQ * NSEQ);
    int mstart = mb ? 7 : 0;
    int mcount = mb ? 6 : 7;

    for (int round = 0; round < 2; ++round) {
        int mi = round * 4 + w;
        if (mi >= mcount) continue;
        int mtile = mstart + mi;

        // q fragments (16 rows x 64 d fp32 -> bf16)
        int gm0 = mtile * 16 + lrow; int gmq = gm0 > 196 ? 196 : gm0;
        const float* qrow = q + (size_t)(b * NSEQ + gmq) * DMODEL + hh * 64;
        bf16x8 aq0 = cvt8(qrow + lq * 8);
        bf16x8 aq1 = cvt8(qrow + 32 + lq * 8);

        // scores: s[nt] at (m = lq*4+r, col = nt*16+lrow)
        f32x4 s[13];
#pragma unroll
        for (int nt = 0; nt < 13; ++nt) {
            int gn = nt * 16 + lrow; if (gn > 196) gn = 196;
            const float* krow = k + (size_t)(b * NSEQ + gn) * DMODEL + hh * 64;
            bf16x8 bk0 = cvt8(krow + lq * 8);
            bf16x8 bk1 = cvt8(krow + 32 + lq * 8);
            f32x4 a = {0.f, 0.f, 0.f, 0.f};
            a = __builtin_amdgcn_mfma_f32_16x16x32_bf16(aq0, bk0, a, 0, 0, 0);
            a = __builtin_amdgcn_mfma_f32_16x16x32_bf16(aq1, bk1, a, 0, 0, 0);
            s[nt] = a;
        }

        // in-register softmax; cols >=197 masked (nt==12 && lrow>=5)
        float rls[4];
        bool colbad = (lrow >= 5);
#pragma unroll
        for (int r = 0; r < 4; ++r) {
            float m1 = -1e30f;
#pragma unroll
            for (int nt = 0; nt < 12; ++nt) m1 = fmaxf(m1, s[nt][r]);
            m1 = fmaxf(m1, colbad ? -1e30f : s[12][r]);
            m1 = fmaxf(m1, __shfl_xor(m1, 1, 64));
            m1 = fmaxf(m1, __shfl_xor(m1, 2, 64));
            m1 = fmaxf(m1, __shfl_xor(m1, 4, 64));
            m1 = fmaxf(m1, __shfl_xor(m1, 8, 64));
            float sm = 0.f;
#pragma unroll
            for (int nt = 0; nt < 13; ++nt) {
                float e = __expf(s[nt][r] - m1);
                if (nt == 12 && colbad) e = 0.f;
                s[nt][r] = e;
                sm += e;
            }
            sm += __shfl_xor(sm, 1, 64);
            sm += __shfl_xor(sm, 2, 64);
            sm += __shfl_xor(sm, 4, 64);
            sm += __shfl_xor(sm, 8, 64);
            rls[r] = 1.f / sm;
        }

        // probs: write-once to global output + bf16 into per-wave swizzled P
#pragma unroll
        for (int nt = 0; nt < 13; ++nt) {
            int gc = nt * 16 + lrow;
            bool cok = (gc < 197);
#pragma unroll
            for (int r = 0; r < 4; ++r) {
                float p = s[nt][r] * rls[r];
                s[nt][r] = p;
                int gm = mtile * 16 + lq * 4 + r;
                if (cok && gm < 197)
                    attnw[pbase + (size_t)gm * 197 + gc] = p;
            }
        }
#pragma unroll
        for (int nt = 0; nt < 13; ++nt) {
#pragma unroll
            for (int r = 0; r < 4; ++r) {
                int m = lq * 4 + r;
                Pw[m * 224 + ((nt * 16 + lrow) ^ (lq << 3))] = f2bf(s[nt][r]);
            }
        }

        // PV: A from swizzled P (same wave -> no barrier), B from vT
        f32x4 o[4];
        const f32x4 zf = {0.f, 0.f, 0.f, 0.f};
#pragma unroll
        for (int n2 = 0; n2 < 4; ++n2) o[n2] = zf;
#pragma unroll
        for (int ks = 0; ks < 7; ++ks) {
            bf16x8 af = *(const bf16x8*)(Pw + lrow * 224 + ((ks * 32 + lq * 8) ^ ((lrow >> 2) << 3)));
#pragma unroll
            for (int n2 = 0; n2 < 4; ++n2) {
                bf16x8 bv = *(const bf16x8*)(&vT[(n2 * 16 + lrow) * 224 + ks * 32 + lq * 8]);
                o[n2] = __builtin_amdgcn_mfma_f32_16x16x32_bf16(af, bv, o[n2], 0, 0, 0);
            }
        }
#pragma unroll
        for (int n2 = 0; n2 < 4; ++n2) {
            int gcol = hh * 64 + n2 * 16 + lrow;
#pragma unroll
            for (int r = 0; r < 4; ++r) {
                int gm = mtile * 16 + lq * 4 + r;
                if (gm < 197) {
                    size_t off = (size_t)(b * NSEQ + gm) * DMODEL + gcol;
                    outf[off] = o[n2][r];
                    outb[off] = f2bf(o[n2][r]);
                }
            }
        }
    }
}

extern "C" void kernel_launch(void* const* d_in, const int* in_sizes, int n_in,
                              void* d_out, int out_size, void* d_ws, size_t ws_size,
                              hipStream_t stream) {
    const float* x    = (const float*)d_in[0];
    const float* ln1g = (const float*)d_in[1];
    const float* ln1b = (const float*)d_in[2];
    const float* wq   = (const float*)d_in[3];
    const float* bq   = (const float*)d_in[4];
    const float* wk   = (const float*)d_in[5];
    const float* bk   = (const float*)d_in[6];
    const float* wv   = (const float*)d_in[7];
    const float* bv   = (const float*)d_in[8];
    const float* wo   = (const float*)d_in[9];
    const float* bo   = (const float*)d_in[10];
    const float* ln2g = (const float*)d_in[11];
    const float* ln2b = (const float*)d_in[12];
    const float* w1   = (const float*)d_in[13];
    const float* b1   = (const float*)d_in[14];
    const float* w2   = (const float*)d_in[15];
    const float* b2   = (const float*)d_in[16];

    float* out     = (float*)d_out;
    float* preproj = out;                 // output 0: 12608*768 fp32
    float* hidden  = out + 9682944;       // output 1: 12608*768 fp32
    float* attnw   = out + 19365888;      // output 2: 64*12*197*197 fp32

    u16* bufA = (u16*)d_ws;               // h -> attn_out(bf16) -> hsn
    u16* bufB = bufA + 9682944;           // v -> woT -> gelu chunk (+wT slots)

    // qkvT [2304][768] bf16 stashed in attnw region (dead until attn_fused)
    u16* qkvT = (u16*)attnw;

    long long tailElems = (long long)(ws_size >> 1) - 19365888LL;
    int CH; u16* w1T;
    if (tailElems >= 1179648LL)      { CH = 768; w1T = bufB + 9682944; }
    else if (tailElems >= 786432LL)  { CH = 512; w1T = bufB + 9682944; }
    else                             { CH = 512; w1T = bufB + 6455296; }
    u16* w2T = w1T + (size_t)CH * 768;
    int NCH = 3072 / CH;

    // LN1: x -> bufA (bf16)
    ln_rows<<<3152, 256, 0, stream>>>(x, ln1g, ln1b, bufA, MROWS);
    // transpose wq|wk|wv -> qkvT (bf16, [n][k])
    wtrans<<<dim3(24, 24), 256, 0, stream>>>(wq, qkvT,           768, 768);
    wtrans<<<dim3(24, 24), 256, 0, stream>>>(wk, qkvT + 589824,  768, 768);
    wtrans<<<dim3(24, 24), 256, 0, stream>>>(wv, qkvT + 1179648, 768, 768);
    // fused QKV: q(fp32*0.125)->preproj, k(fp32)->hidden, v(bf16)->bufB
    gemm_qkv<<<dim3(99, 18), 256, 0, stream>>>(bufA, qkvT, preproj, hidden, bufB,
                                               bq, bk, bv, MROWS);
    // fused attention: probs -> attnw (overwrites qkvT stash), out -> preproj + bufA
    attn_fused<<<1536, 256, 0, stream>>>(preproj, hidden, bufB, attnw, preproj, bufA);
    // woT into bufB (v dead), then out-proj + residual(x) -> hidden
    wtrans<<<dim3(24, 24), 256, 0, stream>>>(wo, bufB, 768, 768);
    gemm_std<64><<<dim3(197, 6), 256, 0, stream>>>(bufA, bufB, hidden, nullptr, bo, x,
                                                   MROWS, 768, 768, 768, 768, 1.f, 0);
    // LN2: hidden -> bufA (bf16 hsn)
    ln_rows<<<3152, 256, 0, stream>>>(hidden, ln2g, ln2b, bufA, MROWS);
    // MLP in DFF chunks of CH
    for (int ci = 0; ci < NCH; ++ci) {
        wtrans<<<dim3(24, CH / 32), 256, 0, stream>>>(w1 + ci * CH, w1T, 3072, 768);
        wtrans<<<dim3(CH / 32, 24), 256, 0, stream>>>(w2 + (size_t)ci * CH * 768, w2T, 768, CH);
        gemm_std<64><<<dim3(197, CH / 128), 256, 0, stream>>>(
            bufA, w1T, nullptr, bufB, b1 + ci * CH, nullptr,
            MROWS, 768, 768, 768, CH, 1.f, 1);
        gemm_std<64><<<dim3(197, 6), 256, 0, stream>>>(
            bufB, w2T, hidden, nullptr, (ci == 0) ? b2 : nullptr, hidden,
            MROWS, CH, CH, CH, 768, 1.f, 0);
    }
}